// Round 1
// baseline (172.765 us; speedup 1.0000x reference)
//
#include <hip/hip_runtime.h>

// ---------------------------------------------------------------------------
// DiffusionModel — algebraically collapsed implementation.
//
// Key identities (exact in real arithmetic):
//   eq_hidden == 0 always  => gate/mix/W_gate/W_mix dead, project = b_proj.
//   pred[s,n,c] = xt[s,n,c]*D1[s,n] + D2[s,n]
//     D1 = mean_h(damping), D2 = mean_h(b_proj*damping)
//     damping = W_damp[:, :H] @ u + (b_damp + Wd[:,H]*cos t + Wd[:,H+1]*sin t)
//   => D1 = w1·u + c1,  D2 = w2·u + c2   (w1,w2,c1,c2 precomputed)
//   u = tanh(W_rec[:, :H] @ hp + b_rec),  hp = W_in @ h[j0] + b_in
//   D1/D2 depend only on node j0 = walks[s,n,0]  => compute per NODE (50k),
//   gather per (s,n) pair (200k).
// ---------------------------------------------------------------------------

constexpr int N_NODES = 50000;
constexpr int F_IN    = 64;
constexpr int H       = 128;
constexpr int S_WALKS = 4;
constexpr int STEPS   = 100;

// workspace layout (float offsets)
constexpr int WS_WINT = 0;                    // W_in transposed: [64][128]
constexpr int WS_W1   = WS_WINT + F_IN * H;   // 8192
constexpr int WS_W2   = WS_W1 + H;            // 8320
constexpr int WS_SC   = WS_W2 + H;            // 8448: sa, sb, c1, c2
constexpr int WS_D12  = WS_SC + 8;            // 8456: interleaved d1,d2 per node
constexpr int WS_PART = WS_D12 + 2 * N_NODES; // 108456: per-wave partials
constexpr int LOSS_BLOCKS = (S_WALKS * N_NODES + 255) / 256; // 782
constexpr int NPART   = LOSS_BLOCKS * 4;      // 4 waves per 256-thread block
// total ws use: (108456 + 3128) * 4B  ~= 447 KB

// ---------------------------------------------------------------------------
// K1: tiny precompute. 1 block, 128 threads.
// ---------------------------------------------------------------------------
__global__ void precompute_kernel(const float* __restrict__ W_in,
                                  const float* __restrict__ W_damp,
                                  const float* __restrict__ b_damp,
                                  const float* __restrict__ b_proj,
                                  const int* __restrict__ t_idx_p,
                                  float* ws) {
  const int t = threadIdx.x; // 128 threads

  // transpose W_in:  WinT[k*H + r] = W_in[r*F_IN + k]
  for (int idx = t; idx < H * F_IN; idx += 128) {
    int r = idx / F_IN, k = idx % F_IN;
    ws[WS_WINT + k * H + r] = W_in[idx];
  }

  const int   ti   = *t_idx_p;
  const float tval = (float)ti / (float)STEPS;
  const float ct = cosf(tval), st = sinf(tval);

  // w1[k] = mean_h W_damp[h][k];  w2[k] = mean_h b_proj[h]*W_damp[h][k]
  if (t < H) {
    float s1 = 0.f, s2 = 0.f;
    for (int h = 0; h < H; ++h) {
      float v = W_damp[h * (H + 2) + t];
      s1 += v;
      s2 += b_proj[h] * v;
    }
    ws[WS_W1 + t] = s1 * (1.0f / H);
    ws[WS_W2 + t] = s2 * (1.0f / H);
  }

  // c1 = mean_h c_damp[h];  c2 = mean_h b_proj[h]*c_damp[h]
  __shared__ float red1[128], red2[128];
  float cd = 0.f, cd2 = 0.f;
  if (t < H) {
    float c = b_damp[t] + W_damp[t * (H + 2) + H] * ct
                        + W_damp[t * (H + 2) + H + 1] * st;
    cd = c;
    cd2 = b_proj[t] * c;
  }
  red1[t] = cd;
  red2[t] = cd2;
  __syncthreads();
  if (t == 0) {
    float s1 = 0.f, s2 = 0.f;
    for (int i = 0; i < H; ++i) { s1 += red1[i]; s2 += red2[i]; }
    ws[WS_SC + 2] = s1 * (1.0f / H);
    ws[WS_SC + 3] = s2 * (1.0f / H);
    // alpha_bar = cumprod(1 - linspace(1e-4, 0.02, STEPS))[t_idx]
    float ab = 1.0f;
    const float step = (0.02f - 0.0001f) / (float)(STEPS - 1);
    for (int i = 0; i <= ti; ++i) {
      float beta = 0.0001f + step * (float)i;
      ab *= (1.0f - beta);
    }
    ws[WS_SC + 0] = sqrtf(ab);
    ws[WS_SC + 1] = sqrtf(1.0f - ab);
  }
}

// ---------------------------------------------------------------------------
// K2: per-node fused pipeline. One lane per node.
//   hp = W_in @ h[n] + b_in          (hp lives in 128 VGPRs, static unroll)
//   u  = tanh(W_rec1 @ hp + b_rec)   (row loop; weights via wave-uniform s_load)
//   d1 = w1·u + c1 ; d2 = w2·u + c2
// 128 threads/block = 128 nodes/block; h tile staged in LDS, stride 65 (+1 pad
// => 2-way bank aliasing which is free on CDNA4).
// ---------------------------------------------------------------------------
__global__ __launch_bounds__(128) void node_kernel(
    const float* __restrict__ hin,
    const float* __restrict__ b_in,
    const float* __restrict__ W_rec,
    const float* __restrict__ b_rec,
    float* ws) {
  __shared__ float h_lds[128 * 65];
  const int t = threadIdx.x;
  const int base = blockIdx.x * 128;

  // stage h tile (128 nodes x 64 feats), coalesced global float4 reads
  for (int i = 0; i < 16; ++i) {
    int f = i * 512 + t * 4;        // flat index into tile
    int node = f >> 6, feat = f & 63;
    float4 v = make_float4(0.f, 0.f, 0.f, 0.f);
    if (base + node < N_NODES)
      v = *(const float4*)(hin + (size_t)(base + node) * F_IN + feat);
    float* dst = &h_lds[node * 65 + feat];
    dst[0] = v.x; dst[1] = v.y; dst[2] = v.z; dst[3] = v.w;
  }
  __syncthreads();

  const float* WinT = ws + WS_WINT;
  const float* w1   = ws + WS_W1;
  const float* w2   = ws + WS_W2;
  const float  c1   = ws[WS_SC + 2];
  const float  c2   = ws[WS_SC + 3];

  // phase 1: hp = W_in @ h + b_in, hp in registers
  float hp[H];
#pragma unroll
  for (int r = 0; r < H; ++r) hp[r] = b_in[r];

  const float* hrow = &h_lds[t * 65];
#pragma unroll 2
  for (int k = 0; k < F_IN; ++k) {
    float hk = hrow[k];
    const float* wc = WinT + k * H;   // uniform address -> s_load
#pragma unroll
    for (int r = 0; r < H; ++r) hp[r] = fmaf(wc[r], hk, hp[r]);
  }

  // phase 2: u = tanh(W_rec1 @ hp + b_rec); accumulate d1, d2
  float d1 = c1, d2 = c2;
#pragma unroll 2
  for (int rp = 0; rp < H; ++rp) {
    const float* wr = W_rec + (size_t)rp * (2 * H);  // uniform -> s_load
    float a0 = 0.f, a1 = 0.f, a2 = 0.f, a3 = 0.f;
#pragma unroll
    for (int r = 0; r < H; r += 4) {
      a0 = fmaf(wr[r + 0], hp[r + 0], a0);
      a1 = fmaf(wr[r + 1], hp[r + 1], a1);
      a2 = fmaf(wr[r + 2], hp[r + 2], a2);
      a3 = fmaf(wr[r + 3], hp[r + 3], a3);
    }
    float u = tanhf((a0 + a1) + (a2 + a3) + b_rec[rp]);
    d1 = fmaf(w1[rp], u, d1);
    d2 = fmaf(w2[rp], u, d2);
  }

  const int n = base + t;
  if (n < N_NODES) {
    ws[WS_D12 + 2 * n]     = d1;
    ws[WS_D12 + 2 * n + 1] = d2;
  }
}

// ---------------------------------------------------------------------------
// K3: loss gather + partial reduction. One thread per (s,n) pair.
// ---------------------------------------------------------------------------
__global__ __launch_bounds__(256) void loss_kernel(
    const float* __restrict__ x,
    const int* __restrict__ walks,
    const float* __restrict__ eps,
    const float* ws,
    float* __restrict__ partials) {
  const int idx = blockIdx.x * 256 + threadIdx.x;
  const float sa = ws[WS_SC + 0];
  const float sb = ws[WS_SC + 1];

  float local = 0.f;
  if (idx < S_WALKS * N_NODES) {
    const int j0 = walks[idx * 2];
    const int j1 = walks[idx * 2 + 1];
    const float d1 = ws[WS_D12 + 2 * j0];
    const float d2 = ws[WS_D12 + 2 * j0 + 1];
#pragma unroll
    for (int c = 0; c < 3; ++c) {
      float e  = eps[idx * 3 + c];
      float xt = fmaf(sa, x[j1 * 3 + c], sb * e);
      float diff = fmaf(xt, d1, d2) - e;
      local = fmaf(diff, diff, local);
    }
  }
  // wave-64 shuffle reduction
  for (int off = 32; off > 0; off >>= 1)
    local += __shfl_down(local, off, 64);
  if ((threadIdx.x & 63) == 0)
    partials[blockIdx.x * 4 + (threadIdx.x >> 6)] = local;
}

// ---------------------------------------------------------------------------
// K4: finalize. Sum per-wave partials, scale by 1/(S*N*3).
// ---------------------------------------------------------------------------
__global__ __launch_bounds__(256) void finalize_kernel(
    const float* __restrict__ partials, int np, float* __restrict__ out) {
  __shared__ float red[256];
  float s = 0.f;
  for (int i = threadIdx.x; i < np; i += 256) s += partials[i];
  red[threadIdx.x] = s;
  __syncthreads();
  for (int w = 128; w > 0; w >>= 1) {
    if (threadIdx.x < w) red[threadIdx.x] += red[threadIdx.x + w];
    __syncthreads();
  }
  if (threadIdx.x == 0)
    out[0] = red[0] * (1.0f / (float)(S_WALKS * N_NODES * 3));
}

// ---------------------------------------------------------------------------
extern "C" void kernel_launch(void* const* d_in, const int* in_sizes, int n_in,
                              void* d_out, int out_size, void* d_ws, size_t ws_size,
                              hipStream_t stream) {
  const float* h      = (const float*)d_in[0];
  const float* x      = (const float*)d_in[1];
  const int*   walks  = (const int*)d_in[2];
  const float* eps    = (const float*)d_in[3];
  const int*   t_idx  = (const int*)d_in[4];
  const float* W_in   = (const float*)d_in[5];
  const float* b_in   = (const float*)d_in[6];
  const float* W_rec  = (const float*)d_in[7];
  const float* b_rec  = (const float*)d_in[8];
  // d_in[9..12] = W_gate/b_gate/W_mix/b_mix: provably dead (eq_hidden == 0)
  const float* W_damp = (const float*)d_in[13];
  const float* b_damp = (const float*)d_in[14];
  // d_in[15] = W_proj: dead (project reduces to b_proj)
  const float* b_proj = (const float*)d_in[16];

  float* ws  = (float*)d_ws;
  float* out = (float*)d_out;

  hipLaunchKernelGGL(precompute_kernel, dim3(1), dim3(128), 0, stream,
                     W_in, W_damp, b_damp, b_proj, t_idx, ws);

  hipLaunchKernelGGL(node_kernel, dim3((N_NODES + 127) / 128), dim3(128), 0,
                     stream, h, b_in, W_rec, b_rec, ws);

  hipLaunchKernelGGL(loss_kernel, dim3(LOSS_BLOCKS), dim3(256), 0, stream,
                     x, walks, eps, ws, ws + WS_PART);

  hipLaunchKernelGGL(finalize_kernel, dim3(1), dim3(256), 0, stream,
                     ws + WS_PART, NPART, out);
}